// Round 16
// baseline (344.401 us; speedup 1.0000x reference)
//
#include <hip/hip_runtime.h>
#include <hip/hip_bf16.h>
#include <math.h>

typedef __attribute__((ext_vector_type(8))) __bf16 bf16x8;
typedef __attribute__((ext_vector_type(4))) float f32x4;
typedef __attribute__((ext_vector_type(16))) float f32x16;

#define HH 256
#define WW 256
#define SCALEF 0.08838834764831845f  // 128^-0.5

__device__ __forceinline__ void gload_lds16(const void* g, void* l) {
    __builtin_amdgcn_global_load_lds(
        (const __attribute__((address_space(1))) void*)g,
        (__attribute__((address_space(3))) void*)l, 16, 0, 0);
}

// ---------------------------------------------------------------------------
// K1 (FUSED PREP): blocks [0,16384): feat0 -> in0T transpose;
// [16384,32768): feat2 -> in1T; [32768,33344): weight repack.
// One dispatch replaces three (saves ~2 launch boundaries; prep_w blocks run
// concurrently with transposes).
// ---------------------------------------------------------------------------
__global__ __launch_bounds__(256) void fused_prep(
    const float* __restrict__ feat0, const float* __restrict__ feat2,
    const float* __restrict__ wq, const float* __restrict__ wk,
    __hip_bfloat16* __restrict__ in0T, __hip_bfloat16* __restrict__ in1T,
    __hip_bfloat16* __restrict__ w3q, __hip_bfloat16* __restrict__ w3k)
{
    int bid = blockIdx.x;
    if (bid < 32768) {
        const float* in = (bid < 16384) ? feat0 : feat2;
        __hip_bfloat16* out = (bid < 16384) ? in0T : in1T;
        int blk = bid & 16383;
        int c0 = (blk & 3) * 32;
        int x0 = ((blk >> 2) & 7) * 32;
        int by = blk >> 5;              // b*256 + y
        int y = by & 255, b = by >> 8;
        __shared__ float tile[32][33];
        int tx = threadIdx.x & 31, ty = threadIdx.x >> 5;   // ty 0..7
#pragma unroll
        for (int i = 0; i < 4; i++) {
            int c = c0 + ty + 8 * i;
            tile[ty + 8 * i][tx] = in[(((size_t)b * 128 + c) * HH + y) * WW + x0 + tx];
        }
        __syncthreads();
        int tx2 = threadIdx.x & 15;     // channel pair 0..15
        int xi = threadIdx.x >> 4;      // 0..15
#pragma unroll
        for (int ii = 0; ii < 2; ii++) {
            int xl = xi + 16 * ii;
            union { __hip_bfloat16 h[2]; unsigned u; } pk;
            pk.h[0] = __float2bfloat16(tile[2 * tx2][xl]);
            pk.h[1] = __float2bfloat16(tile[2 * tx2 + 1][xl]);
            *(unsigned*)(out + (((size_t)b * HH + y) * WW + x0 + xl) * 128 + c0 + 2 * tx2) = pk.u;
        }
    } else {
        // weight repack -> K16-chunk-major, lane-contiguous 32x32x16 B frags
        int i = (bid - 32768) * 256 + threadIdx.x;
        if (i >= 128 * 128 * 9) return;
        int co = i / (128 * 9);
        int r = i - co * 128 * 9;
        int ci = r / 9;
        int tap = r - ci * 9;
        int kg = tap * 128 + ci;
        int qc = kg >> 4;
        int kin = kg & 15;
        int dst = qc * 2048 + (co >> 5) * 512 + (kin >> 3) * 256 + (co & 31) * 8 + (kin & 7);
        w3q[dst] = __float2bfloat16(wq[i]);
        w3k[dst] = __float2bfloat16(wk[i]);
    }
}

// ---------------------------------------------------------------------------
// K3: conv3x3 (SAME) implicit GEMM, q+k merged, 32x32x16 MFMA.
// K32-PAIR build (r14 base, 152 us) + T5 s_setprio around MFMA clusters
// (2 blocks/CU at independent pair-phases -> arbitration has something to do).
// ---------------------------------------------------------------------------
__global__ __launch_bounds__(256, 2) void conv3x3_mfma(
    const __hip_bfloat16* __restrict__ in0, const __hip_bfloat16* __restrict__ in1,
    const __hip_bfloat16* __restrict__ w3q, const __hip_bfloat16* __restrict__ w3k,
    const float* __restrict__ bq, const float* __restrict__ bk,
    __hip_bfloat16* __restrict__ q0, __hip_bfloat16* __restrict__ k0,
    __hip_bfloat16* __restrict__ q2, __hip_bfloat16* __restrict__ k2)
{
    const int half = blockIdx.y;          // 0: in0 -> (q0,k0), 1: in1 -> (q2,k2)
    const __hip_bfloat16* src = half ? in1 : in0;
    __hip_bfloat16* qdst = half ? q2 : q0;
    __hip_bfloat16* kdst = half ? k2 : k0;

    const int blk = blockIdx.x;           // 0..1023
    const int b = blk >> 9;
    const int rr = blk & 511;
    const int y0 = (rr >> 4) << 3;        // 32 tile-rows of 8
    const int x0 = (rr & 15) << 4;        // 16 tile-cols of 16

    __shared__ __align__(16) char smem[46080 + 4 * 8192];  // patch + B 4x8KB
    char* patch = smem;
    char* ldsB = smem + 46080;

    const int tid = threadIdx.x;

    // ---- stage input halo patch (10x18 pos, 16 slots each, slot-XOR swizzle)
    for (int idx = tid; idx < 2880; idx += 256) {
        int p = idx >> 4, lc = idx & 15;
        int py = p / 18, px_ = p - py * 18;
        int gy = y0 + py - 1, gx = x0 + px_ - 1;
        uint4 v = make_uint4(0u, 0u, 0u, 0u);
        if (gy >= 0 && gy < HH && gx >= 0 && gx < WW)
            v = *(const uint4*)(src + ((((size_t)b * HH + gy) * WW + gx) << 7) + lc * 8);
        *(uint4*)(patch + p * 256 + (((lc & 8) | ((lc ^ p) & 7)) << 4)) = v;
    }
    // ---- async-stage pair 0 (chunks 0,1) into bufs 0,1 ----
    {
        const char* sq = (const char*)w3q + tid * 16;
        const char* sk = (const char*)w3k + tid * 16;
#pragma unroll
        for (int cb = 0; cb < 2; ++cb) {
            char* dl = ldsB + cb * 8192 + tid * 16;
            gload_lds16(sq + cb * 4096, dl);
            gload_lds16(sk + cb * 4096, dl + 4096);
        }
    }
    __syncthreads();   // full drain (patch + pair 0)

    const int lane = tid & 63;
    const int wv = tid >> 6;
    const int p = wv >> 1, c = wv & 1;
    const int l31 = lane & 31;
    const int ks = lane >> 5;             // k-half within K16
    const int rowl = (lane >> 4) & 1;     // row within frag's 2 tile-rows
    const int coll = lane & 15;           // tile col
    const int ybase = p * 4;
    const int cN0 = c * 2048 + lane * 16; // B frag n=0 byte offset
    const int cN1 = cN0 + 1024;          // n=1

    f32x16 accq[2][2], acck[2][2];
#pragma unroll
    for (int m = 0; m < 2; ++m)
#pragma unroll
        for (int n = 0; n < 2; ++n) {
            accq[m][n] = (f32x16)(0.f);
            acck[m][n] = (f32x16)(0.f);
        }

#pragma unroll
    for (int q = 0; q < 72; ++q) {
        const int tap = q >> 3, cc8 = q & 7;
        const int ky = tap / 3, kx = tap - ky * 3;
        if ((q & 1) == 0 && q + 2 < 72) { // pair start: prefetch next pair
            const char* sq = (const char*)w3q + (size_t)(q + 2) * 4096 + tid * 16;
            const char* sk = (const char*)w3k + (size_t)(q + 2) * 4096 + tid * 16;
            char* dl2 = ldsB + ((q + 2) & 3) * 8192 + tid * 16;
            char* dl3 = ldsB + ((q + 3) & 3) * 8192 + tid * 16;
            gload_lds16(sq, dl2);
            gload_lds16(sk, dl2 + 4096);
            gload_lds16(sq + 4096, dl3);
            gload_lds16(sk + 4096, dl3 + 4096);
        }
        const char* bb = ldsB + (q & 3) * 8192;
        bf16x8 fq0 = *(const bf16x8*)(bb + cN0);
        bf16x8 fq1 = *(const bf16x8*)(bb + cN1);
        bf16x8 fk0 = *(const bf16x8*)(bb + 4096 + cN0);
        bf16x8 fk1 = *(const bf16x8*)(bb + 4096 + cN1);
        const int s = cc8 * 2 + ks;       // 16B slot within 256B channel row
        __builtin_amdgcn_s_setprio(1);
#pragma unroll
        for (int m = 0; m < 2; ++m) {
            int pos = (ybase + m * 2 + rowl + ky) * 18 + coll + kx;
            bf16x8 a = *(const bf16x8*)(patch + pos * 256 +
                                        (((s & 8) | ((s ^ pos) & 7)) << 4));
            accq[m][0] = __builtin_amdgcn_mfma_f32_32x32x16_bf16(a, fq0, accq[m][0], 0, 0, 0);
            accq[m][1] = __builtin_amdgcn_mfma_f32_32x32x16_bf16(a, fq1, accq[m][1], 0, 0, 0);
            acck[m][0] = __builtin_amdgcn_mfma_f32_32x32x16_bf16(a, fk0, acck[m][0], 0, 0, 0);
            acck[m][1] = __builtin_amdgcn_mfma_f32_32x32x16_bf16(a, fk1, acck[m][1], 0, 0, 0);
        }
        __builtin_amdgcn_s_setprio(0);
        if ((q & 1) == 1 && q + 1 < 72) { // pair end: one drain+barrier per pair
            asm volatile("s_waitcnt vmcnt(0)" ::: "memory");
            __builtin_amdgcn_s_barrier();
            __builtin_amdgcn_sched_barrier(0);
        }
    }
    __syncthreads();   // all patch/B reads done before stage overwrite

    // ---- epilogue: 32x32 C/D map, stage bf16 [128 px][stride 136] over patch
    float bvq[2] = { bq[c * 64 + l31], bq[c * 64 + 32 + l31] };
    float bvk[2] = { bk[c * 64 + l31], bk[c * 64 + 32 + l31] };
    __hip_bfloat16* stage = (__hip_bfloat16*)patch;

#pragma unroll
    for (int m = 0; m < 2; ++m)
#pragma unroll
        for (int n = 0; n < 2; ++n)
#pragma unroll
            for (int reg = 0; reg < 16; ++reg) {
                int px = p * 64 + m * 32 + (reg & 3) + 8 * (reg >> 2) + 4 * ks;
                stage[px * 136 + c * 64 + n * 32 + l31] =
                    __float2bfloat16(accq[m][n][reg] + bvq[n]);
            }
    __syncthreads();
#pragma unroll
    for (int it = 0; it < 8; ++it) {
        int idx = it * 256 + tid;
        int px = idx >> 4, lc = idx & 15;
        int y = y0 + (px >> 4), x = x0 + (px & 15);
        uint4 v = *(const uint4*)((const char*)patch + px * 272 + lc * 16);
        *(uint4*)(qdst + ((((size_t)b * HH + y) * WW + x) << 7) + lc * 8) = v;
    }
    __syncthreads();   // q-stage reads done before k-stage overwrite
#pragma unroll
    for (int m = 0; m < 2; ++m)
#pragma unroll
        for (int n = 0; n < 2; ++n)
#pragma unroll
            for (int reg = 0; reg < 16; ++reg) {
                int px = p * 64 + m * 32 + (reg & 3) + 8 * (reg >> 2) + 4 * ks;
                stage[px * 136 + c * 64 + n * 32 + l31] =
                    __float2bfloat16(acck[m][n][reg] + bvk[n]);
            }
    __syncthreads();
#pragma unroll
    for (int it = 0; it < 8; ++it) {
        int idx = it * 256 + tid;
        int px = idx >> 4, lc = idx & 15;
        int y = y0 + (px >> 4), x = x0 + (px & 15);
        uint4 v = *(const uint4*)((const char*)patch + px * 272 + lc * 16);
        *(uint4*)(kdst + ((((size_t)b * HH + y) * WW + x) << 7) + lc * 8) = v;
    }
}

// ---------------------------------------------------------------------------
// K4: per-(window, estimate x shift) correlation + flow_bsd + flow_mid.
// Q in registers; K staged in LDS (linear 256B rows, XOR-preswizzled source).
// cls aliases kt -> LDS ~19KB -> 5 blocks/CU (launch_bounds(256,5)).
// Softmax: no-max, mask constant -40 (shift-invariant on fully-masked rows).
// ---------------------------------------------------------------------------
#define CST 66       // cls row stride (floats)
__global__ __launch_bounds__(256, 5) void window_flow(
    const __hip_bfloat16* __restrict__ q0, const __hip_bfloat16* __restrict__ k0,
    const __hip_bfloat16* __restrict__ q2, const __hip_bfloat16* __restrict__ k2,
    const float* __restrict__ btab,
    float* __restrict__ f1e0, float* __restrict__ f1e1,
    float* __restrict__ f0e0, float* __restrict__ f0e1)
{
    const int id = blockIdx.x;               // 0..16383
    const int xcd = id & 7;
    const int slot = id >> 3;
    const int combo = slot & 7;               // 8 combos adjacent on one XCD
    const int wdx = (slot >> 3) * 8 + xcd;    // 0..2047

    const int e = combo >> 2;
    const int sflag = combo & 3;
    const int shq = (sflag >> 1) & 1;
    const int swq = sflag & 1;
    const int sh = shq ? 4 : 0, sw = swq ? 4 : 0;
    const __hip_bfloat16* qf = e ? q2 : q0;
    const __hip_bfloat16* kf = e ? k0 : k2;
    float* f1 = e ? f1e1 : f1e0;
    float* f0 = e ? f0e1 : f0e0;

    const int b = wdx >> 10;
    const int s1i = (wdx >> 5) & 31;
    const int s2i = wdx & 31;

    __shared__ __align__(16) char wsm[16896];   // kt (16KB) ALIASED by cls (16.9KB)
    __hip_bfloat16* kt = (__hip_bfloat16*)wsm;
    float* cls = (float*)wsm;
    __shared__ float cmid[81], fxm[81], fym[81];
    __shared__ float sb[225];

    const int tid = threadIdx.x;
    const int lane = tid & 63;
    const int wv = tid >> 6;
    const int l15 = lane & 15;
    const int kq = lane >> 4;

    // ---- Q fragments: direct global->register (A operand of 16x16x32) ----
    bf16x8 qreg[4];
    {
        int qp = wv * 16 + l15;               // q window pixel
        int qiy = qp >> 3, qix = qp & 7;
        int qgy = (s1i * 8 + qiy + sh) & 255;
        int qgx = (s2i * 8 + qix + sw) & 255;
        const __hip_bfloat16* qb = qf + ((((size_t)b * HH + qgy) * WW + qgx) << 7) + kq * 8;
#pragma unroll
        for (int kc = 0; kc < 4; ++kc)
            qreg[kc] = *(const bf16x8*)(qb + kc * 32);
    }

    // ---- K staging: linear LDS dest, XOR-preswizzled global source ----
    for (int idx = tid; idx < 1024; idx += 256) {
        int p = idx >> 4, lc = idx & 15;
        int iy = p >> 3, ix = p & 7;
        int gy = (s1i * 8 + iy + sh) & 255;
        int gx = (s2i * 8 + ix + sw) & 255;
        const __hip_bfloat16* g = kf + ((((size_t)b * HH + gy) * WW + gx) << 7)
                                     + ((lc ^ (p & 7)) << 3);
        gload_lds16(g, kt + p * 128 + lc * 8);
    }
    if (tid < 225) sb[tid] = btab[tid];
    __syncthreads();   // drains DMA + q-loads + sb

    // corr = qw . kw^T   (M=64, N=64, K=128), 4 waves over M
    f32x4 acc[4];
#pragma unroll
    for (int nf = 0; nf < 4; nf++) acc[nf] = (f32x4){0.f, 0.f, 0.f, 0.f};

#pragma unroll
    for (int kc = 0; kc < 4; ++kc) {
        const int swz = ((kc * 4 + kq) ^ (l15 & 7)) << 4;   // row&7 == l15&7 for B
        bf16x8 a = qreg[kc];
#pragma unroll
        for (int nf = 0; nf < 4; ++nf) {
            bf16x8 bb = *(const bf16x8*)((const char*)kt + (nf * 16 + l15) * 256 + swz);
            acc[nf] = __builtin_amdgcn_mfma_f32_16x16x32_bf16(a, bb, acc[nf], 0, 0, 0);
        }
    }
    __syncthreads();   // kt reads complete before cls overwrites (alias)

    // epilogue: scale + relative-pos bias (+ shift mask only on boundary windows)
    const bool needm = (shq && s1i == 31) || (swq && s2i == 31);
#pragma unroll
    for (int nf = 0; nf < 4; ++nf) {
#pragma unroll
        for (int r = 0; r < 4; ++r) {
            int row = wv * 16 + kq * 4 + r;
            int col = nf * 16 + l15;
            int qy = row >> 3, qx = row & 7;
            int ty = col >> 3, tx = col & 7;
            float v = acc[nf][r] * SCALEF + sb[(qy - ty + 7) * 15 + (qx - tx + 7)];
            if (needm) {
                int rhq = 0, rwq = 0, rht = 0, rwt = 0;
                if (shq && s1i == 31) { rhq = (qy < 4) ? 1 : 2; rht = (ty < 4) ? 1 : 2; }
                if (swq && s2i == 31) { rwq = (qx < 4) ? 1 : 2; rwt = (tx < 4) ? 1 : 2; }
                int regq, regt;
                if (shq && swq) { regq = rhq * 3 + rwq; regt = rht * 3 + rwt; }
                else if (shq)   { regq = rhq; regt = rht; }
                else            { regq = rwq; regt = rwt; }
                if (regq != regt) v -= 40.0f;
            }
            cls[row * CST + col] = v;
        }
    }
    __syncthreads();

    const int rg = tid >> 4;       // 16 row-groups
    const int lg = tid & 15;       // 16 lanes per row

    // ---- flow_bsd: 16 rows, 16-lane groups, no-max softmax ----
    {
        int fy = rg >> 2, fx = rg & 3;
        int qy = fy + 2, qx = fx + 2;
        const float* rowp = &cls[(qy * 8 + qx) * CST];
        float S = 0.f, sx = 0.f, sy = 0.f;
#pragma unroll
        for (int j = 0; j < 4; ++j) {
            int t = lg * 4 + j;
            float p = __expf(rowp[t]);
            S += p; sx += p * (float)(t & 7); sy += p * (float)(t >> 3);
        }
#pragma unroll
        for (int m = 8; m >= 1; m >>= 1) {
            S += __shfl_xor(S, m); sx += __shfl_xor(sx, m); sy += __shfl_xor(sy, m);
        }
        if (lg == 0) {
            float fxv = sx / S - (float)qx;
            float fyv = sy / S - (float)qy;
            int Y = (s1i * 8 + shq * 4 + fy + 2) & 255;
            int X = (s2i * 8 + swq * 4 + fx + 2) & 255;
            size_t base = (size_t)b * 2 * HH * WW;
            f0[base + (size_t)Y * WW + X] = fxv;
            f0[base + (size_t)HH * WW + (size_t)Y * WW + X] = fyv;
        }
    }

    // ---- flow_mid row softmaxes: 81 rows, 16 at a time, no-max ----
    int offj[4], h2j[4], w2j[4];
#pragma unroll
    for (int j = 0; j < 4; ++j) {
        int t = lg + 16 * j;
        h2j[j] = t >> 3; w2j[j] = t & 7;
        offj[j] = t - h2j[j] * (8 * CST) - w2j[j] * CST;
    }
    for (int it = 0; it < 6; ++it) {
        int rm = it * 16 + rg;
        if (rm < 81) {
            int a = rm / 9, bc = rm - a * 9;
            int ay = a + 3, bx = bc + 3;
            int base = (ay * 8 + bx) * CST;
            float S = 0.f, sc = 0.f, sx = 0.f, sy = 0.f;
#pragma unroll
            for (int j = 0; j < 4; ++j) {
                float v = 0.0f;
                if ((unsigned)(ay - h2j[j]) < 8u && (unsigned)(bx - w2j[j]) < 8u)
                    v = cls[base + offj[j]];
                float p = __expf(v);
                S += p; sc += v * p;
                sx += p * (float)w2j[j]; sy += p * (float)h2j[j];
            }
#pragma unroll
            for (int m = 8; m >= 1; m >>= 1) {
                S += __shfl_xor(S, m); sc += __shfl_xor(sc, m);
                sx += __shfl_xor(sx, m); sy += __shfl_xor(sy, m);
            }
            if (lg == 0) {
                float inv = 1.0f / S;
                cmid[rm] = sc * inv;
                fxm[rm] = sx * inv - (float)bx * 0.5f;
                fym[rm] = sy * inv - (float)ay * 0.5f;
            }
        }
    }
    __syncthreads();

    // flow_mid quadrant combine -> 8x8 (no-max softmax over 4)
    if (tid < 64) {
        int fy = tid >> 3, fx = tid & 7;
        int i00 = fy * 9 + fx, i01 = i00 + 1, i10 = i00 + 9, i11 = i00 + 10;
        float p0 = __expf(cmid[i00]), p1 = __expf(cmid[i01]);
        float p2 = __expf(cmid[i10]), p3 = __expf(cmid[i11]);
        float S = p0 + p1 + p2 + p3;
        float ox = 2.0f * (p0 * fxm[i00] + p1 * fxm[i01] + p2 * fxm[i10] + p3 * fxm[i11]) / S;
        float oy = 2.0f * (p0 * fym[i00] + p1 * fym[i01] + p2 * fym[i10] + p3 * fym[i11]) / S;
        int Y = (s1i * 16 + shq * 8 + fy + 4) & 511;
        int X = (s2i * 16 + swq * 8 + fx + 4) & 511;
        size_t base = (size_t)b * 2 * 512 * 512;
        f1[base + (size_t)Y * 512 + X] = ox;
        f1[base + (size_t)512 * 512 + (size_t)Y * 512 + X] = oy;
    }
}

// ---------------------------------------------------------------------------
// K5: bilinear resize (half-pixel, edge clamp) + scale, concat 4 outputs
// ---------------------------------------------------------------------------
__global__ __launch_bounds__(256) void resize_out(
    const float* __restrict__ f1e0, const float* __restrict__ f1e1,
    const float* __restrict__ f0e0, const float* __restrict__ f0e1,
    float* __restrict__ out)
{
    int idx = blockIdx.x * 256 + threadIdx.x;       // 0 .. 16777215
    int o = idx >> 22;
    int rem = idx & 4194303;
    int bc = rem >> 20;                              // b*2+ch
    int Y = (rem >> 10) & 1023;
    int X = rem & 1023;
    const float* src; int n; float invf, sc;
    if (o == 0)      { src = f1e1; n = 512; invf = 0.5f;  sc = 2.f; }
    else if (o == 1) { src = f1e0; n = 512; invf = 0.5f;  sc = 2.f; }
    else if (o == 2) { src = f0e0; n = 256; invf = 0.25f; sc = 4.f; }
    else             { src = f0e1; n = 256; invf = 0.25f; sc = 4.f; }
    float syf = ((float)Y + 0.5f) * invf - 0.5f;
    float sxf = ((float)X + 0.5f) * invf - 0.5f;
    int iy = (int)floorf(syf), ix = (int)floorf(sxf);
    float wy = syf - (float)iy, wx = sxf - (float)ix;
    int y0c = min(max(iy, 0), n - 1), y1c = min(max(iy + 1, 0), n - 1);
    int x0c = min(max(ix, 0), n - 1), x1c = min(max(ix + 1, 0), n - 1);
    const float* s = src + (size_t)bc * n * n;
    float v00 = s[(size_t)y0c * n + x0c], v01 = s[(size_t)y0c * n + x1c];
    float v10 = s[(size_t)y1c * n + x0c], v11 = s[(size_t)y1c * n + x1c];
    float v = (1.f - wy) * ((1.f - wx) * v00 + wx * v01) + wy * ((1.f - wx) * v10 + wx * v11);
    out[idx] = v * sc;
}

// ---------------------------------------------------------------------------
extern "C" void kernel_launch(void* const* d_in, const int* in_sizes, int n_in,
                              void* d_out, int out_size, void* d_ws, size_t ws_size,
                              hipStream_t stream)
{
    const float* feat0 = (const float*)d_in[0];
    const float* feat2 = (const float*)d_in[1];
    const float* wq = (const float*)d_in[2];
    const float* bq = (const float*)d_in[3];
    const float* wk = (const float*)d_in[4];
    const float* bk = (const float*)d_in[5];
    const float* btab = (const float*)d_in[6];

    char* w = (char*)d_ws;
    const size_t F = (size_t)16777216 * 2;   // bytes per bf16 NHWC field (2*256*256*128)
    __hip_bfloat16* q0 = (__hip_bfloat16*)(w);
    __hip_bfloat16* k0 = (__hip_bfloat16*)(w + F);
    __hip_bfloat16* q2 = (__hip_bfloat16*)(w + 2 * F);
    __hip_bfloat16* k2 = (__hip_bfloat16*)(w + 3 * F);
    __hip_bfloat16* in0T = (__hip_bfloat16*)(w + 4 * F);
    __hip_bfloat16* in1T = (__hip_bfloat16*)(w + 5 * F);
    __hip_bfloat16* w3q = (__hip_bfloat16*)(w + 6 * F);
    __hip_bfloat16* w3k = (__hip_bfloat16*)(w + 6 * F + 294912);
    float* f1e0 = (float*)(w + 6 * F + 2 * 294912);
    float* f1e1 = f1e0 + 1048576;   // 2*2*512*512
    float* f0e0 = f1e1 + 1048576;
    float* f0e1 = f0e0 + 262144;    // 2*2*256*256

    hipLaunchKernelGGL(fused_prep, dim3(33344), dim3(256), 0, stream,
                       feat0, feat2, wq, wk, in0T, in1T, w3q, w3k);
    hipLaunchKernelGGL(conv3x3_mfma, dim3(1024, 2), dim3(256), 0, stream,
                       in0T, in1T, w3q, w3k, bq, bk, q0, k0, q2, k2);
    hipLaunchKernelGGL(window_flow, dim3(16384), dim3(256), 0, stream,
                       q0, k0, q2, k2, btab, f1e0, f1e1, f0e0, f0e1);
    hipLaunchKernelGGL(resize_out, dim3(65536), dim3(256), 0, stream,
                       f1e0, f1e1, f0e0, f0e1, (float*)d_out);
}

// Round 17
// 335.335 us; speedup vs baseline: 1.0270x; 1.0270x over previous
//
#include <hip/hip_runtime.h>
#include <hip/hip_bf16.h>
#include <math.h>

typedef __attribute__((ext_vector_type(8))) __bf16 bf16x8;
typedef __attribute__((ext_vector_type(4))) float f32x4;
typedef __attribute__((ext_vector_type(16))) float f32x16;

#define HH 256
#define WW 256
#define SCALEF 0.08838834764831845f  // 128^-0.5

__device__ __forceinline__ void gload_lds16(const void* g, void* l) {
    __builtin_amdgcn_global_load_lds(
        (const __attribute__((address_space(1))) void*)g,
        (__attribute__((address_space(3))) void*)l, 16, 0, 0);
}

// ---------------------------------------------------------------------------
// K1 (FUSED PREP): blocks [0,16384): feat0 -> in0T transpose;
// [16384,32768): feat2 -> in1T; [32768,33344): weight repack.
// ---------------------------------------------------------------------------
__global__ __launch_bounds__(256) void fused_prep(
    const float* __restrict__ feat0, const float* __restrict__ feat2,
    const float* __restrict__ wq, const float* __restrict__ wk,
    __hip_bfloat16* __restrict__ in0T, __hip_bfloat16* __restrict__ in1T,
    __hip_bfloat16* __restrict__ w3q, __hip_bfloat16* __restrict__ w3k)
{
    int bid = blockIdx.x;
    if (bid < 32768) {
        const float* in = (bid < 16384) ? feat0 : feat2;
        __hip_bfloat16* out = (bid < 16384) ? in0T : in1T;
        int blk = bid & 16383;
        int c0 = (blk & 3) * 32;
        int x0 = ((blk >> 2) & 7) * 32;
        int by = blk >> 5;              // b*256 + y
        int y = by & 255, b = by >> 8;
        __shared__ float tile[32][33];
        int tx = threadIdx.x & 31, ty = threadIdx.x >> 5;   // ty 0..7
#pragma unroll
        for (int i = 0; i < 4; i++) {
            int c = c0 + ty + 8 * i;
            tile[ty + 8 * i][tx] = in[(((size_t)b * 128 + c) * HH + y) * WW + x0 + tx];
        }
        __syncthreads();
        int tx2 = threadIdx.x & 15;     // channel pair 0..15
        int xi = threadIdx.x >> 4;      // 0..15
#pragma unroll
        for (int ii = 0; ii < 2; ii++) {
            int xl = xi + 16 * ii;
            union { __hip_bfloat16 h[2]; unsigned u; } pk;
            pk.h[0] = __float2bfloat16(tile[2 * tx2][xl]);
            pk.h[1] = __float2bfloat16(tile[2 * tx2 + 1][xl]);
            *(unsigned*)(out + (((size_t)b * HH + y) * WW + x0 + xl) * 128 + c0 + 2 * tx2) = pk.u;
        }
    } else {
        // weight repack -> K16-chunk-major, lane-contiguous 32x32x16 B frags
        int i = (bid - 32768) * 256 + threadIdx.x;
        if (i >= 128 * 128 * 9) return;
        int co = i / (128 * 9);
        int r = i - co * 128 * 9;
        int ci = r / 9;
        int tap = r - ci * 9;
        int kg = tap * 128 + ci;
        int qc = kg >> 4;
        int kin = kg & 15;
        int dst = qc * 2048 + (co >> 5) * 512 + (kin >> 3) * 256 + (co & 31) * 8 + (kin & 7);
        w3q[dst] = __float2bfloat16(wq[i]);
        w3k[dst] = __float2bfloat16(wk[i]);
    }
}

// ---------------------------------------------------------------------------
// K3: conv3x3 (SAME) implicit GEMM, q+k merged, 32x32x16 MFMA.
// K32-PAIR build (r14, best measured 152 us): 4 LDS B-buffers, one
// vmcnt(0)+s_barrier per pair (35 sync events). NO setprio (r16 A/B: -9.5us).
// ---------------------------------------------------------------------------
__global__ __launch_bounds__(256, 2) void conv3x3_mfma(
    const __hip_bfloat16* __restrict__ in0, const __hip_bfloat16* __restrict__ in1,
    const __hip_bfloat16* __restrict__ w3q, const __hip_bfloat16* __restrict__ w3k,
    const float* __restrict__ bq, const float* __restrict__ bk,
    __hip_bfloat16* __restrict__ q0, __hip_bfloat16* __restrict__ k0,
    __hip_bfloat16* __restrict__ q2, __hip_bfloat16* __restrict__ k2)
{
    const int half = blockIdx.y;          // 0: in0 -> (q0,k0), 1: in1 -> (q2,k2)
    const __hip_bfloat16* src = half ? in1 : in0;
    __hip_bfloat16* qdst = half ? q2 : q0;
    __hip_bfloat16* kdst = half ? k2 : k0;

    const int blk = blockIdx.x;           // 0..1023
    const int b = blk >> 9;
    const int rr = blk & 511;
    const int y0 = (rr >> 4) << 3;        // 32 tile-rows of 8
    const int x0 = (rr & 15) << 4;        // 16 tile-cols of 16

    __shared__ __align__(16) char smem[46080 + 4 * 8192];  // patch + B 4x8KB
    char* patch = smem;
    char* ldsB = smem + 46080;

    const int tid = threadIdx.x;

    // ---- stage input halo patch (10x18 pos, 16 slots each, slot-XOR swizzle)
    for (int idx = tid; idx < 2880; idx += 256) {
        int p = idx >> 4, lc = idx & 15;
        int py = p / 18, px_ = p - py * 18;
        int gy = y0 + py - 1, gx = x0 + px_ - 1;
        uint4 v = make_uint4(0u, 0u, 0u, 0u);
        if (gy >= 0 && gy < HH && gx >= 0 && gx < WW)
            v = *(const uint4*)(src + ((((size_t)b * HH + gy) * WW + gx) << 7) + lc * 8);
        *(uint4*)(patch + p * 256 + (((lc & 8) | ((lc ^ p) & 7)) << 4)) = v;
    }
    // ---- async-stage pair 0 (chunks 0,1) into bufs 0,1 ----
    {
        const char* sq = (const char*)w3q + tid * 16;
        const char* sk = (const char*)w3k + tid * 16;
#pragma unroll
        for (int cb = 0; cb < 2; ++cb) {
            char* dl = ldsB + cb * 8192 + tid * 16;
            gload_lds16(sq + cb * 4096, dl);
            gload_lds16(sk + cb * 4096, dl + 4096);
        }
    }
    __syncthreads();   // full drain (patch + pair 0)

    const int lane = tid & 63;
    const int wv = tid >> 6;
    const int p = wv >> 1, c = wv & 1;
    const int l31 = lane & 31;
    const int ks = lane >> 5;             // k-half within K16
    const int rowl = (lane >> 4) & 1;     // row within frag's 2 tile-rows
    const int coll = lane & 15;           // tile col
    const int ybase = p * 4;
    const int cN0 = c * 2048 + lane * 16; // B frag n=0 byte offset
    const int cN1 = cN0 + 1024;          // n=1

    f32x16 accq[2][2], acck[2][2];
#pragma unroll
    for (int m = 0; m < 2; ++m)
#pragma unroll
        for (int n = 0; n < 2; ++n) {
            accq[m][n] = (f32x16)(0.f);
            acck[m][n] = (f32x16)(0.f);
        }

#pragma unroll
    for (int q = 0; q < 72; ++q) {
        const int tap = q >> 3, cc8 = q & 7;
        const int ky = tap / 3, kx = tap - ky * 3;
        if ((q & 1) == 0 && q + 2 < 72) { // pair start: prefetch next pair
            const char* sq = (const char*)w3q + (size_t)(q + 2) * 4096 + tid * 16;
            const char* sk = (const char*)w3k + (size_t)(q + 2) * 4096 + tid * 16;
            char* dl2 = ldsB + ((q + 2) & 3) * 8192 + tid * 16;
            char* dl3 = ldsB + ((q + 3) & 3) * 8192 + tid * 16;
            gload_lds16(sq, dl2);
            gload_lds16(sk, dl2 + 4096);
            gload_lds16(sq + 4096, dl3);
            gload_lds16(sk + 4096, dl3 + 4096);
        }
        const char* bb = ldsB + (q & 3) * 8192;
        bf16x8 fq0 = *(const bf16x8*)(bb + cN0);
        bf16x8 fq1 = *(const bf16x8*)(bb + cN1);
        bf16x8 fk0 = *(const bf16x8*)(bb + 4096 + cN0);
        bf16x8 fk1 = *(const bf16x8*)(bb + 4096 + cN1);
        const int s = cc8 * 2 + ks;       // 16B slot within 256B channel row
#pragma unroll
        for (int m = 0; m < 2; ++m) {
            int pos = (ybase + m * 2 + rowl + ky) * 18 + coll + kx;
            bf16x8 a = *(const bf16x8*)(patch + pos * 256 +
                                        (((s & 8) | ((s ^ pos) & 7)) << 4));
            accq[m][0] = __builtin_amdgcn_mfma_f32_32x32x16_bf16(a, fq0, accq[m][0], 0, 0, 0);
            accq[m][1] = __builtin_amdgcn_mfma_f32_32x32x16_bf16(a, fq1, accq[m][1], 0, 0, 0);
            acck[m][0] = __builtin_amdgcn_mfma_f32_32x32x16_bf16(a, fk0, acck[m][0], 0, 0, 0);
            acck[m][1] = __builtin_amdgcn_mfma_f32_32x32x16_bf16(a, fk1, acck[m][1], 0, 0, 0);
        }
        if ((q & 1) == 1 && q + 1 < 72) { // pair end: one drain+barrier per pair
            asm volatile("s_waitcnt vmcnt(0)" ::: "memory");
            __builtin_amdgcn_s_barrier();
            __builtin_amdgcn_sched_barrier(0);
        }
    }
    __syncthreads();   // all patch/B reads done before stage overwrite

    // ---- epilogue: 32x32 C/D map, stage bf16 [128 px][stride 136] over patch
    float bvq[2] = { bq[c * 64 + l31], bq[c * 64 + 32 + l31] };
    float bvk[2] = { bk[c * 64 + l31], bk[c * 64 + 32 + l31] };
    __hip_bfloat16* stage = (__hip_bfloat16*)patch;

#pragma unroll
    for (int m = 0; m < 2; ++m)
#pragma unroll
        for (int n = 0; n < 2; ++n)
#pragma unroll
            for (int reg = 0; reg < 16; ++reg) {
                int px = p * 64 + m * 32 + (reg & 3) + 8 * (reg >> 2) + 4 * ks;
                stage[px * 136 + c * 64 + n * 32 + l31] =
                    __float2bfloat16(accq[m][n][reg] + bvq[n]);
            }
    __syncthreads();
#pragma unroll
    for (int it = 0; it < 8; ++it) {
        int idx = it * 256 + tid;
        int px = idx >> 4, lc = idx & 15;
        int y = y0 + (px >> 4), x = x0 + (px & 15);
        uint4 v = *(const uint4*)((const char*)patch + px * 272 + lc * 16);
        *(uint4*)(qdst + ((((size_t)b * HH + y) * WW + x) << 7) + lc * 8) = v;
    }
    __syncthreads();   // q-stage reads done before k-stage overwrite
#pragma unroll
    for (int m = 0; m < 2; ++m)
#pragma unroll
        for (int n = 0; n < 2; ++n)
#pragma unroll
            for (int reg = 0; reg < 16; ++reg) {
                int px = p * 64 + m * 32 + (reg & 3) + 8 * (reg >> 2) + 4 * ks;
                stage[px * 136 + c * 64 + n * 32 + l31] =
                    __float2bfloat16(acck[m][n][reg] + bvk[n]);
            }
    __syncthreads();
#pragma unroll
    for (int it = 0; it < 8; ++it) {
        int idx = it * 256 + tid;
        int px = idx >> 4, lc = idx & 15;
        int y = y0 + (px >> 4), x = x0 + (px & 15);
        uint4 v = *(const uint4*)((const char*)patch + px * 272 + lc * 16);
        *(uint4*)(kdst + ((((size_t)b * HH + y) * WW + x) << 7) + lc * 8) = v;
    }
}

// ---------------------------------------------------------------------------
// K4: per-(window, estimate x shift) correlation + flow_bsd + flow_mid.
// Q in registers; K staged in LDS (linear 256B rows, XOR-preswizzled source).
// cls aliases kt -> LDS ~19KB -> 5 blocks/CU (launch_bounds(256,5)).
// Softmax: no-max, mask constant -40 (shift-invariant on fully-masked rows).
// ---------------------------------------------------------------------------
#define CST 66       // cls row stride (floats)
__global__ __launch_bounds__(256, 5) void window_flow(
    const __hip_bfloat16* __restrict__ q0, const __hip_bfloat16* __restrict__ k0,
    const __hip_bfloat16* __restrict__ q2, const __hip_bfloat16* __restrict__ k2,
    const float* __restrict__ btab,
    float* __restrict__ f1e0, float* __restrict__ f1e1,
    float* __restrict__ f0e0, float* __restrict__ f0e1)
{
    const int id = blockIdx.x;               // 0..16383
    const int xcd = id & 7;
    const int slot = id >> 3;
    const int combo = slot & 7;               // 8 combos adjacent on one XCD
    const int wdx = (slot >> 3) * 8 + xcd;    // 0..2047

    const int e = combo >> 2;
    const int sflag = combo & 3;
    const int shq = (sflag >> 1) & 1;
    const int swq = sflag & 1;
    const int sh = shq ? 4 : 0, sw = swq ? 4 : 0;
    const __hip_bfloat16* qf = e ? q2 : q0;
    const __hip_bfloat16* kf = e ? k0 : k2;
    float* f1 = e ? f1e1 : f1e0;
    float* f0 = e ? f0e1 : f0e0;

    const int b = wdx >> 10;
    const int s1i = (wdx >> 5) & 31;
    const int s2i = wdx & 31;

    __shared__ __align__(16) char wsm[16896];   // kt (16KB) ALIASED by cls (16.9KB)
    __hip_bfloat16* kt = (__hip_bfloat16*)wsm;
    float* cls = (float*)wsm;
    __shared__ float cmid[81], fxm[81], fym[81];
    __shared__ float sb[225];

    const int tid = threadIdx.x;
    const int lane = tid & 63;
    const int wv = tid >> 6;
    const int l15 = lane & 15;
    const int kq = lane >> 4;

    // ---- Q fragments: direct global->register (A operand of 16x16x32) ----
    bf16x8 qreg[4];
    {
        int qp = wv * 16 + l15;               // q window pixel
        int qiy = qp >> 3, qix = qp & 7;
        int qgy = (s1i * 8 + qiy + sh) & 255;
        int qgx = (s2i * 8 + qix + sw) & 255;
        const __hip_bfloat16* qb = qf + ((((size_t)b * HH + qgy) * WW + qgx) << 7) + kq * 8;
#pragma unroll
        for (int kc = 0; kc < 4; ++kc)
            qreg[kc] = *(const bf16x8*)(qb + kc * 32);
    }

    // ---- K staging: linear LDS dest, XOR-preswizzled global source ----
    for (int idx = tid; idx < 1024; idx += 256) {
        int p = idx >> 4, lc = idx & 15;
        int iy = p >> 3, ix = p & 7;
        int gy = (s1i * 8 + iy + sh) & 255;
        int gx = (s2i * 8 + ix + sw) & 255;
        const __hip_bfloat16* g = kf + ((((size_t)b * HH + gy) * WW + gx) << 7)
                                     + ((lc ^ (p & 7)) << 3);
        gload_lds16(g, kt + p * 128 + lc * 8);
    }
    if (tid < 225) sb[tid] = btab[tid];
    __syncthreads();   // drains DMA + q-loads + sb

    // corr = qw . kw^T   (M=64, N=64, K=128), 4 waves over M
    f32x4 acc[4];
#pragma unroll
    for (int nf = 0; nf < 4; nf++) acc[nf] = (f32x4){0.f, 0.f, 0.f, 0.f};

#pragma unroll
    for (int kc = 0; kc < 4; ++kc) {
        const int swz = ((kc * 4 + kq) ^ (l15 & 7)) << 4;   // row&7 == l15&7 for B
        bf16x8 a = qreg[kc];
#pragma unroll
        for (int nf = 0; nf < 4; ++nf) {
            bf16x8 bb = *(const bf16x8*)((const char*)kt + (nf * 16 + l15) * 256 + swz);
            acc[nf] = __builtin_amdgcn_mfma_f32_16x16x32_bf16(a, bb, acc[nf], 0, 0, 0);
        }
    }
    __syncthreads();   // kt reads complete before cls overwrites (alias)

    // epilogue: scale + relative-pos bias (+ shift mask only on boundary windows)
    const bool needm = (shq && s1i == 31) || (swq && s2i == 31);
#pragma unroll
    for (int nf = 0; nf < 4; ++nf) {
#pragma unroll
        for (int r = 0; r < 4; ++r) {
            int row = wv * 16 + kq * 4 + r;
            int col = nf * 16 + l15;
            int qy = row >> 3, qx = row & 7;
            int ty = col >> 3, tx = col & 7;
            float v = acc[nf][r] * SCALEF + sb[(qy - ty + 7) * 15 + (qx - tx + 7)];
            if (needm) {
                int rhq = 0, rwq = 0, rht = 0, rwt = 0;
                if (shq && s1i == 31) { rhq = (qy < 4) ? 1 : 2; rht = (ty < 4) ? 1 : 2; }
                if (swq && s2i == 31) { rwq = (qx < 4) ? 1 : 2; rwt = (tx < 4) ? 1 : 2; }
                int regq, regt;
                if (shq && swq) { regq = rhq * 3 + rwq; regt = rht * 3 + rwt; }
                else if (shq)   { regq = rhq; regt = rht; }
                else            { regq = rwq; regt = rwt; }
                if (regq != regt) v -= 40.0f;
            }
            cls[row * CST + col] = v;
        }
    }
    __syncthreads();

    const int rg = tid >> 4;       // 16 row-groups
    const int lg = tid & 15;       // 16 lanes per row

    // ---- flow_bsd: 16 rows, 16-lane groups, no-max softmax ----
    {
        int fy = rg >> 2, fx = rg & 3;
        int qy = fy + 2, qx = fx + 2;
        const float* rowp = &cls[(qy * 8 + qx) * CST];
        float S = 0.f, sx = 0.f, sy = 0.f;
#pragma unroll
        for (int j = 0; j < 4; ++j) {
            int t = lg * 4 + j;
            float p = __expf(rowp[t]);
            S += p; sx += p * (float)(t & 7); sy += p * (float)(t >> 3);
        }
#pragma unroll
        for (int m = 8; m >= 1; m >>= 1) {
            S += __shfl_xor(S, m); sx += __shfl_xor(sx, m); sy += __shfl_xor(sy, m);
        }
        if (lg == 0) {
            float fxv = sx / S - (float)qx;
            float fyv = sy / S - (float)qy;
            int Y = (s1i * 8 + shq * 4 + fy + 2) & 255;
            int X = (s2i * 8 + swq * 4 + fx + 2) & 255;
            size_t base = (size_t)b * 2 * HH * WW;
            f0[base + (size_t)Y * WW + X] = fxv;
            f0[base + (size_t)HH * WW + (size_t)Y * WW + X] = fyv;
        }
    }

    // ---- flow_mid row softmaxes: 81 rows, 16 at a time, no-max ----
    int offj[4], h2j[4], w2j[4];
#pragma unroll
    for (int j = 0; j < 4; ++j) {
        int t = lg + 16 * j;
        h2j[j] = t >> 3; w2j[j] = t & 7;
        offj[j] = t - h2j[j] * (8 * CST) - w2j[j] * CST;
    }
    for (int it = 0; it < 6; ++it) {
        int rm = it * 16 + rg;
        if (rm < 81) {
            int a = rm / 9, bc = rm - a * 9;
            int ay = a + 3, bx = bc + 3;
            int base = (ay * 8 + bx) * CST;
            float S = 0.f, sc = 0.f, sx = 0.f, sy = 0.f;
#pragma unroll
            for (int j = 0; j < 4; ++j) {
                float v = 0.0f;
                if ((unsigned)(ay - h2j[j]) < 8u && (unsigned)(bx - w2j[j]) < 8u)
                    v = cls[base + offj[j]];
                float p = __expf(v);
                S += p; sc += v * p;
                sx += p * (float)w2j[j]; sy += p * (float)h2j[j];
            }
#pragma unroll
            for (int m = 8; m >= 1; m >>= 1) {
                S += __shfl_xor(S, m); sc += __shfl_xor(sc, m);
                sx += __shfl_xor(sx, m); sy += __shfl_xor(sy, m);
            }
            if (lg == 0) {
                float inv = 1.0f / S;
                cmid[rm] = sc * inv;
                fxm[rm] = sx * inv - (float)bx * 0.5f;
                fym[rm] = sy * inv - (float)ay * 0.5f;
            }
        }
    }
    __syncthreads();

    // flow_mid quadrant combine -> 8x8 (no-max softmax over 4)
    if (tid < 64) {
        int fy = tid >> 3, fx = tid & 7;
        int i00 = fy * 9 + fx, i01 = i00 + 1, i10 = i00 + 9, i11 = i00 + 10;
        float p0 = __expf(cmid[i00]), p1 = __expf(cmid[i01]);
        float p2 = __expf(cmid[i10]), p3 = __expf(cmid[i11]);
        float S = p0 + p1 + p2 + p3;
        float ox = 2.0f * (p0 * fxm[i00] + p1 * fxm[i01] + p2 * fxm[i10] + p3 * fxm[i11]) / S;
        float oy = 2.0f * (p0 * fym[i00] + p1 * fym[i01] + p2 * fym[i10] + p3 * fym[i11]) / S;
        int Y = (s1i * 16 + shq * 8 + fy + 4) & 511;
        int X = (s2i * 16 + swq * 8 + fx + 4) & 511;
        size_t base = (size_t)b * 2 * 512 * 512;
        f1[base + (size_t)Y * 512 + X] = ox;
        f1[base + (size_t)512 * 512 + (size_t)Y * 512 + X] = oy;
    }
}

// ---------------------------------------------------------------------------
// K5: bilinear resize (half-pixel, edge clamp) + scale, concat 4 outputs
// ---------------------------------------------------------------------------
__global__ __launch_bounds__(256) void resize_out(
    const float* __restrict__ f1e0, const float* __restrict__ f1e1,
    const float* __restrict__ f0e0, const float* __restrict__ f0e1,
    float* __restrict__ out)
{
    int idx = blockIdx.x * 256 + threadIdx.x;       // 0 .. 16777215
    int o = idx >> 22;
    int rem = idx & 4194303;
    int bc = rem >> 20;                              // b*2+ch
    int Y = (rem >> 10) & 1023;
    int X = rem & 1023;
    const float* src; int n; float invf, sc;
    if (o == 0)      { src = f1e1; n = 512; invf = 0.5f;  sc = 2.f; }
    else if (o == 1) { src = f1e0; n = 512; invf = 0.5f;  sc = 2.f; }
    else if (o == 2) { src = f0e0; n = 256; invf = 0.25f; sc = 4.f; }
    else             { src = f0e1; n = 256; invf = 0.25f; sc = 4.f; }
    float syf = ((float)Y + 0.5f) * invf - 0.5f;
    float sxf = ((float)X + 0.5f) * invf - 0.5f;
    int iy = (int)floorf(syf), ix = (int)floorf(sxf);
    float wy = syf - (float)iy, wx = sxf - (float)ix;
    int y0c = min(max(iy, 0), n - 1), y1c = min(max(iy + 1, 0), n - 1);
    int x0c = min(max(ix, 0), n - 1), x1c = min(max(ix + 1, 0), n - 1);
    const float* s = src + (size_t)bc * n * n;
    float v00 = s[(size_t)y0c * n + x0c], v01 = s[(size_t)y0c * n + x1c];
    float v10 = s[(size_t)y1c * n + x0c], v11 = s[(size_t)y1c * n + x1c];
    float v = (1.f - wy) * ((1.f - wx) * v00 + wx * v01) + wy * ((1.f - wx) * v10 + wx * v11);
    out[idx] = v * sc;
}

// ---------------------------------------------------------------------------
extern "C" void kernel_launch(void* const* d_in, const int* in_sizes, int n_in,
                              void* d_out, int out_size, void* d_ws, size_t ws_size,
                              hipStream_t stream)
{
    const float* feat0 = (const float*)d_in[0];
    const float* feat2 = (const float*)d_in[1];
    const float* wq = (const float*)d_in[2];
    const float* bq = (const float*)d_in[3];
    const float* wk = (const float*)d_in[4];
    const float* bk = (const float*)d_in[5];
    const float* btab = (const float*)d_in[6];

    char* w = (char*)d_ws;
    const size_t F = (size_t)16777216 * 2;   // bytes per bf16 NHWC field (2*256*256*128)
    __hip_bfloat16* q0 = (__hip_bfloat16*)(w);
    __hip_bfloat16* k0 = (__hip_bfloat16*)(w + F);
    __hip_bfloat16* q2 = (__hip_bfloat16*)(w + 2 * F);
    __hip_bfloat16* k2 = (__hip_bfloat16*)(w + 3 * F);
    __hip_bfloat16* in0T = (__hip_bfloat16*)(w + 4 * F);
    __hip_bfloat16* in1T = (__hip_bfloat16*)(w + 5 * F);
    __hip_bfloat16* w3q = (__hip_bfloat16*)(w + 6 * F);
    __hip_bfloat16* w3k = (__hip_bfloat16*)(w + 6 * F + 294912);
    float* f1e0 = (float*)(w + 6 * F + 2 * 294912);
    float* f1e1 = f1e0 + 1048576;   // 2*2*512*512
    float* f0e0 = f1e1 + 1048576;
    float* f0e1 = f0e0 + 262144;    // 2*2*256*256

    hipLaunchKernelGGL(fused_prep, dim3(33344), dim3(256), 0, stream,
                       feat0, feat2, wq, wk, in0T, in1T, w3q, w3k);
    hipLaunchKernelGGL(conv3x3_mfma, dim3(1024, 2), dim3(256), 0, stream,
                       in0T, in1T, w3q, w3k, bq, bk, q0, k0, q2, k2);
    hipLaunchKernelGGL(window_flow, dim3(16384), dim3(256), 0, stream,
                       q0, k0, q2, k2, btab, f1e0, f1e1, f0e0, f0e1);
    hipLaunchKernelGGL(resize_out, dim3(65536), dim3(256), 0, stream,
                       f1e0, f1e1, f0e0, f0e1, (float*)d_out);
}

// Round 18
// 294.369 us; speedup vs baseline: 1.1700x; 1.1392x over previous
//
#include <hip/hip_runtime.h>
#include <hip/hip_bf16.h>
#include <math.h>

typedef __attribute__((ext_vector_type(8))) __bf16 bf16x8;
typedef __attribute__((ext_vector_type(4))) float f32x4;
typedef __attribute__((ext_vector_type(16))) float f32x16;

#define HH 256
#define WW 256
#define SCALEF 0.08838834764831845f  // 128^-0.5

__device__ __forceinline__ void gload_lds16(const void* g, void* l) {
    __builtin_amdgcn_global_load_lds(
        (const __attribute__((address_space(1))) void*)g,
        (__attribute__((address_space(3))) void*)l, 16, 0, 0);
}

// ---------------------------------------------------------------------------
// K1 (FUSED PREP): blocks [0,16384): feat0 -> in0T transpose;
// [16384,32768): feat2 -> in1T; [32768,33344): weight repack.
// ---------------------------------------------------------------------------
__global__ __launch_bounds__(256) void fused_prep(
    const float* __restrict__ feat0, const float* __restrict__ feat2,
    const float* __restrict__ wq, const float* __restrict__ wk,
    __hip_bfloat16* __restrict__ in0T, __hip_bfloat16* __restrict__ in1T,
    __hip_bfloat16* __restrict__ w3q, __hip_bfloat16* __restrict__ w3k)
{
    int bid = blockIdx.x;
    if (bid < 32768) {
        const float* in = (bid < 16384) ? feat0 : feat2;
        __hip_bfloat16* out = (bid < 16384) ? in0T : in1T;
        int blk = bid & 16383;
        int c0 = (blk & 3) * 32;
        int x0 = ((blk >> 2) & 7) * 32;
        int by = blk >> 5;              // b*256 + y
        int y = by & 255, b = by >> 8;
        __shared__ float tile[32][33];
        int tx = threadIdx.x & 31, ty = threadIdx.x >> 5;   // ty 0..7
#pragma unroll
        for (int i = 0; i < 4; i++) {
            int c = c0 + ty + 8 * i;
            tile[ty + 8 * i][tx] = in[(((size_t)b * 128 + c) * HH + y) * WW + x0 + tx];
        }
        __syncthreads();
        int tx2 = threadIdx.x & 15;     // channel pair 0..15
        int xi = threadIdx.x >> 4;      // 0..15
#pragma unroll
        for (int ii = 0; ii < 2; ii++) {
            int xl = xi + 16 * ii;
            union { __hip_bfloat16 h[2]; unsigned u; } pk;
            pk.h[0] = __float2bfloat16(tile[2 * tx2][xl]);
            pk.h[1] = __float2bfloat16(tile[2 * tx2 + 1][xl]);
            *(unsigned*)(out + (((size_t)b * HH + y) * WW + x0 + xl) * 128 + c0 + 2 * tx2) = pk.u;
        }
    } else {
        // weight repack -> K16-chunk-major, lane-contiguous 32x32x16 B frags
        int i = (bid - 32768) * 256 + threadIdx.x;
        if (i >= 128 * 128 * 9) return;
        int co = i / (128 * 9);
        int r = i - co * 128 * 9;
        int ci = r / 9;
        int tap = r - ci * 9;
        int kg = tap * 128 + ci;
        int qc = kg >> 4;
        int kin = kg & 15;
        int dst = qc * 2048 + (co >> 5) * 512 + (kin >> 3) * 256 + (co & 31) * 8 + (kin & 7);
        w3q[dst] = __float2bfloat16(wq[i]);
        w3k[dst] = __float2bfloat16(wk[i]);
    }
}

// ---------------------------------------------------------------------------
// K3: conv3x3 (SAME) implicit GEMM, q+k merged, 32x32x16 MFMA.
// K32-PAIR build (r14, best measured 152 us): 4 LDS B-buffers, one
// vmcnt(0)+s_barrier per pair (35 sync events). No setprio (r16: -9.5us).
// ---------------------------------------------------------------------------
__global__ __launch_bounds__(256, 2) void conv3x3_mfma(
    const __hip_bfloat16* __restrict__ in0, const __hip_bfloat16* __restrict__ in1,
    const __hip_bfloat16* __restrict__ w3q, const __hip_bfloat16* __restrict__ w3k,
    const float* __restrict__ bq, const float* __restrict__ bk,
    __hip_bfloat16* __restrict__ q0, __hip_bfloat16* __restrict__ k0,
    __hip_bfloat16* __restrict__ q2, __hip_bfloat16* __restrict__ k2)
{
    const int half = blockIdx.y;          // 0: in0 -> (q0,k0), 1: in1 -> (q2,k2)
    const __hip_bfloat16* src = half ? in1 : in0;
    __hip_bfloat16* qdst = half ? q2 : q0;
    __hip_bfloat16* kdst = half ? k2 : k0;

    const int blk = blockIdx.x;           // 0..1023
    const int b = blk >> 9;
    const int rr = blk & 511;
    const int y0 = (rr >> 4) << 3;        // 32 tile-rows of 8
    const int x0 = (rr & 15) << 4;        // 16 tile-cols of 16

    __shared__ __align__(16) char smem[46080 + 4 * 8192];  // patch + B 4x8KB
    char* patch = smem;
    char* ldsB = smem + 46080;

    const int tid = threadIdx.x;

    // ---- stage input halo patch (10x18 pos, 16 slots each, slot-XOR swizzle)
    for (int idx = tid; idx < 2880; idx += 256) {
        int p = idx >> 4, lc = idx & 15;
        int py = p / 18, px_ = p - py * 18;
        int gy = y0 + py - 1, gx = x0 + px_ - 1;
        uint4 v = make_uint4(0u, 0u, 0u, 0u);
        if (gy >= 0 && gy < HH && gx >= 0 && gx < WW)
            v = *(const uint4*)(src + ((((size_t)b * HH + gy) * WW + gx) << 7) + lc * 8);
        *(uint4*)(patch + p * 256 + (((lc & 8) | ((lc ^ p) & 7)) << 4)) = v;
    }
    // ---- async-stage pair 0 (chunks 0,1) into bufs 0,1 ----
    {
        const char* sq = (const char*)w3q + tid * 16;
        const char* sk = (const char*)w3k + tid * 16;
#pragma unroll
        for (int cb = 0; cb < 2; ++cb) {
            char* dl = ldsB + cb * 8192 + tid * 16;
            gload_lds16(sq + cb * 4096, dl);
            gload_lds16(sk + cb * 4096, dl + 4096);
        }
    }
    __syncthreads();   // full drain (patch + pair 0)

    const int lane = tid & 63;
    const int wv = tid >> 6;
    const int p = wv >> 1, c = wv & 1;
    const int l31 = lane & 31;
    const int ks = lane >> 5;             // k-half within K16
    const int rowl = (lane >> 4) & 1;     // row within frag's 2 tile-rows
    const int coll = lane & 15;           // tile col
    const int ybase = p * 4;
    const int cN0 = c * 2048 + lane * 16; // B frag n=0 byte offset
    const int cN1 = cN0 + 1024;          // n=1

    f32x16 accq[2][2], acck[2][2];
#pragma unroll
    for (int m = 0; m < 2; ++m)
#pragma unroll
        for (int n = 0; n < 2; ++n) {
            accq[m][n] = (f32x16)(0.f);
            acck[m][n] = (f32x16)(0.f);
        }

#pragma unroll
    for (int q = 0; q < 72; ++q) {
        const int tap = q >> 3, cc8 = q & 7;
        const int ky = tap / 3, kx = tap - ky * 3;
        if ((q & 1) == 0 && q + 2 < 72) { // pair start: prefetch next pair
            const char* sq = (const char*)w3q + (size_t)(q + 2) * 4096 + tid * 16;
            const char* sk = (const char*)w3k + (size_t)(q + 2) * 4096 + tid * 16;
            char* dl2 = ldsB + ((q + 2) & 3) * 8192 + tid * 16;
            char* dl3 = ldsB + ((q + 3) & 3) * 8192 + tid * 16;
            gload_lds16(sq, dl2);
            gload_lds16(sk, dl2 + 4096);
            gload_lds16(sq + 4096, dl3);
            gload_lds16(sk + 4096, dl3 + 4096);
        }
        const char* bb = ldsB + (q & 3) * 8192;
        bf16x8 fq0 = *(const bf16x8*)(bb + cN0);
        bf16x8 fq1 = *(const bf16x8*)(bb + cN1);
        bf16x8 fk0 = *(const bf16x8*)(bb + 4096 + cN0);
        bf16x8 fk1 = *(const bf16x8*)(bb + 4096 + cN1);
        const int s = cc8 * 2 + ks;       // 16B slot within 256B channel row
#pragma unroll
        for (int m = 0; m < 2; ++m) {
            int pos = (ybase + m * 2 + rowl + ky) * 18 + coll + kx;
            bf16x8 a = *(const bf16x8*)(patch + pos * 256 +
                                        (((s & 8) | ((s ^ pos) & 7)) << 4));
            accq[m][0] = __builtin_amdgcn_mfma_f32_32x32x16_bf16(a, fq0, accq[m][0], 0, 0, 0);
            accq[m][1] = __builtin_amdgcn_mfma_f32_32x32x16_bf16(a, fq1, accq[m][1], 0, 0, 0);
            acck[m][0] = __builtin_amdgcn_mfma_f32_32x32x16_bf16(a, fk0, acck[m][0], 0, 0, 0);
            acck[m][1] = __builtin_amdgcn_mfma_f32_32x32x16_bf16(a, fk1, acck[m][1], 0, 0, 0);
        }
        if ((q & 1) == 1 && q + 1 < 72) { // pair end: one drain+barrier per pair
            asm volatile("s_waitcnt vmcnt(0)" ::: "memory");
            __builtin_amdgcn_s_barrier();
            __builtin_amdgcn_sched_barrier(0);
        }
    }
    __syncthreads();   // all patch/B reads done before stage overwrite

    // ---- epilogue: 32x32 C/D map, stage bf16 [128 px][stride 136] over patch
    float bvq[2] = { bq[c * 64 + l31], bq[c * 64 + 32 + l31] };
    float bvk[2] = { bk[c * 64 + l31], bk[c * 64 + 32 + l31] };
    __hip_bfloat16* stage = (__hip_bfloat16*)patch;

#pragma unroll
    for (int m = 0; m < 2; ++m)
#pragma unroll
        for (int n = 0; n < 2; ++n)
#pragma unroll
            for (int reg = 0; reg < 16; ++reg) {
                int px = p * 64 + m * 32 + (reg & 3) + 8 * (reg >> 2) + 4 * ks;
                stage[px * 136 + c * 64 + n * 32 + l31] =
                    __float2bfloat16(accq[m][n][reg] + bvq[n]);
            }
    __syncthreads();
#pragma unroll
    for (int it = 0; it < 8; ++it) {
        int idx = it * 256 + tid;
        int px = idx >> 4, lc = idx & 15;
        int y = y0 + (px >> 4), x = x0 + (px & 15);
        uint4 v = *(const uint4*)((const char*)patch + px * 272 + lc * 16);
        *(uint4*)(qdst + ((((size_t)b * HH + y) * WW + x) << 7) + lc * 8) = v;
    }
    __syncthreads();   // q-stage reads done before k-stage overwrite
#pragma unroll
    for (int m = 0; m < 2; ++m)
#pragma unroll
        for (int n = 0; n < 2; ++n)
#pragma unroll
            for (int reg = 0; reg < 16; ++reg) {
                int px = p * 64 + m * 32 + (reg & 3) + 8 * (reg >> 2) + 4 * ks;
                stage[px * 136 + c * 64 + n * 32 + l31] =
                    __float2bfloat16(acck[m][n][reg] + bvk[n]);
            }
    __syncthreads();
#pragma unroll
    for (int it = 0; it < 8; ++it) {
        int idx = it * 256 + tid;
        int px = idx >> 4, lc = idx & 15;
        int y = y0 + (px >> 4), x = x0 + (px & 15);
        uint4 v = *(const uint4*)((const char*)patch + px * 272 + lc * 16);
        *(uint4*)(kdst + ((((size_t)b * HH + y) * WW + x) << 7) + lc * 8) = v;
    }
}

// ---------------------------------------------------------------------------
// K4: per-(window, estimate x shift) correlation + flow_bsd + flow_mid.
// Q in registers; K staged in LDS (linear 256B rows, XOR-preswizzled source).
// cls aliases kt -> LDS ~19KB -> 5 blocks/CU.
// flow_mid reduction reshaped: 4-lane groups x 16 terms, 2 passes, 2-step
// shuffle ladders (~10 shfl/thread vs 96 in the 16-lane/6-pass shape).
// Softmax: no-max, mask constant -40 (shift-invariant on fully-masked rows).
// ---------------------------------------------------------------------------
#define CST 66       // cls row stride (floats)
__global__ __launch_bounds__(256, 5) void window_flow(
    const __hip_bfloat16* __restrict__ q0, const __hip_bfloat16* __restrict__ k0,
    const __hip_bfloat16* __restrict__ q2, const __hip_bfloat16* __restrict__ k2,
    const float* __restrict__ btab,
    float* __restrict__ f1e0, float* __restrict__ f1e1,
    float* __restrict__ f0e0, float* __restrict__ f0e1)
{
    const int id = blockIdx.x;               // 0..16383
    const int xcd = id & 7;
    const int slot = id >> 3;
    const int combo = slot & 7;               // 8 combos adjacent on one XCD
    const int wdx = (slot >> 3) * 8 + xcd;    // 0..2047

    const int e = combo >> 2;
    const int sflag = combo & 3;
    const int shq = (sflag >> 1) & 1;
    const int swq = sflag & 1;
    const int sh = shq ? 4 : 0, sw = swq ? 4 : 0;
    const __hip_bfloat16* qf = e ? q2 : q0;
    const __hip_bfloat16* kf = e ? k0 : k2;
    float* f1 = e ? f1e1 : f1e0;
    float* f0 = e ? f0e1 : f0e0;

    const int b = wdx >> 10;
    const int s1i = (wdx >> 5) & 31;
    const int s2i = wdx & 31;

    __shared__ __align__(16) char wsm[16896];   // kt (16KB) ALIASED by cls (16.9KB)
    __hip_bfloat16* kt = (__hip_bfloat16*)wsm;
    float* cls = (float*)wsm;
    __shared__ float cmid[81], fxm[81], fym[81];
    __shared__ float sb[225];

    const int tid = threadIdx.x;
    const int lane = tid & 63;
    const int wv = tid >> 6;
    const int l15 = lane & 15;
    const int kq = lane >> 4;

    // ---- Q fragments: direct global->register (A operand of 16x16x32) ----
    bf16x8 qreg[4];
    {
        int qp = wv * 16 + l15;               // q window pixel
        int qiy = qp >> 3, qix = qp & 7;
        int qgy = (s1i * 8 + qiy + sh) & 255;
        int qgx = (s2i * 8 + qix + sw) & 255;
        const __hip_bfloat16* qb = qf + ((((size_t)b * HH + qgy) * WW + qgx) << 7) + kq * 8;
#pragma unroll
        for (int kc = 0; kc < 4; ++kc)
            qreg[kc] = *(const bf16x8*)(qb + kc * 32);
    }

    // ---- K staging: linear LDS dest, XOR-preswizzled global source ----
    for (int idx = tid; idx < 1024; idx += 256) {
        int p = idx >> 4, lc = idx & 15;
        int iy = p >> 3, ix = p & 7;
        int gy = (s1i * 8 + iy + sh) & 255;
        int gx = (s2i * 8 + ix + sw) & 255;
        const __hip_bfloat16* g = kf + ((((size_t)b * HH + gy) * WW + gx) << 7)
                                     + ((lc ^ (p & 7)) << 3);
        gload_lds16(g, kt + p * 128 + lc * 8);
    }
    if (tid < 225) sb[tid] = btab[tid];
    __syncthreads();   // drains DMA + q-loads + sb

    // corr = qw . kw^T   (M=64, N=64, K=128), 4 waves over M
    f32x4 acc[4];
#pragma unroll
    for (int nf = 0; nf < 4; nf++) acc[nf] = (f32x4){0.f, 0.f, 0.f, 0.f};

#pragma unroll
    for (int kc = 0; kc < 4; ++kc) {
        const int swz = ((kc * 4 + kq) ^ (l15 & 7)) << 4;   // row&7 == l15&7 for B
        bf16x8 a = qreg[kc];
#pragma unroll
        for (int nf = 0; nf < 4; ++nf) {
            bf16x8 bb = *(const bf16x8*)((const char*)kt + (nf * 16 + l15) * 256 + swz);
            acc[nf] = __builtin_amdgcn_mfma_f32_16x16x32_bf16(a, bb, acc[nf], 0, 0, 0);
        }
    }
    __syncthreads();   // kt reads complete before cls overwrites (alias)

    // epilogue: scale + relative-pos bias (+ shift mask only on boundary windows)
    const bool needm = (shq && s1i == 31) || (swq && s2i == 31);
#pragma unroll
    for (int nf = 0; nf < 4; ++nf) {
#pragma unroll
        for (int r = 0; r < 4; ++r) {
            int row = wv * 16 + kq * 4 + r;
            int col = nf * 16 + l15;
            int qy = row >> 3, qx = row & 7;
            int ty = col >> 3, tx = col & 7;
            float v = acc[nf][r] * SCALEF + sb[(qy - ty + 7) * 15 + (qx - tx + 7)];
            if (needm) {
                int rhq = 0, rwq = 0, rht = 0, rwt = 0;
                if (shq && s1i == 31) { rhq = (qy < 4) ? 1 : 2; rht = (ty < 4) ? 1 : 2; }
                if (swq && s2i == 31) { rwq = (qx < 4) ? 1 : 2; rwt = (tx < 4) ? 1 : 2; }
                int regq, regt;
                if (shq && swq) { regq = rhq * 3 + rwq; regt = rht * 3 + rwt; }
                else if (shq)   { regq = rhq; regt = rht; }
                else            { regq = rwq; regt = rwt; }
                if (regq != regt) v -= 40.0f;
            }
            cls[row * CST + col] = v;
        }
    }
    __syncthreads();

    const int rg = tid >> 4;       // 16 row-groups (bsd)
    const int lg = tid & 15;       // 16 lanes per row (bsd)

    // ---- flow_bsd: 16 rows, 16-lane groups, no-max softmax ----
    {
        int fy = rg >> 2, fx = rg & 3;
        int qy = fy + 2, qx = fx + 2;
        const float* rowp = &cls[(qy * 8 + qx) * CST];
        float S = 0.f, sx = 0.f, sy = 0.f;
#pragma unroll
        for (int j = 0; j < 4; ++j) {
            int t = lg * 4 + j;
            float p = __expf(rowp[t]);
            S += p; sx += p * (float)(t & 7); sy += p * (float)(t >> 3);
        }
#pragma unroll
        for (int m = 8; m >= 1; m >>= 1) {
            S += __shfl_xor(S, m); sx += __shfl_xor(sx, m); sy += __shfl_xor(sy, m);
        }
        if (lg == 0) {
            float fxv = sx / S - (float)qx;
            float fyv = sy / S - (float)qy;
            int Y = (s1i * 8 + shq * 4 + fy + 2) & 255;
            int X = (s2i * 8 + swq * 4 + fx + 2) & 255;
            size_t base = (size_t)b * 2 * HH * WW;
            f0[base + (size_t)Y * WW + X] = fxv;
            f0[base + (size_t)HH * WW + (size_t)Y * WW + X] = fyv;
        }
    }

    // ---- flow_mid row softmaxes: 4-lane groups x 16 terms, 2 passes ----
    {
        const int g4 = tid >> 2;      // 64 groups
        const int q4 = tid & 3;       // lane within group
#pragma unroll
        for (int pass = 0; pass < 2; ++pass) {
            int rm = pass * 64 + g4;
            if (rm < 81) {
                int a = rm / 9, bc = rm - a * 9;
                int ay = a + 3, bx = bc + 3;
                int base = (ay * 8 + bx) * CST;
                float S = 0.f, sc = 0.f, sx = 0.f, sy = 0.f;
#pragma unroll
                for (int i = 0; i < 16; ++i) {
                    int t = q4 + 4 * i;
                    int h2 = t >> 3, w2 = t & 7;
                    float v = 0.0f;
                    if ((unsigned)(ay - h2) < 8u && (unsigned)(bx - w2) < 8u)
                        v = cls[base + t - h2 * (8 * CST) - w2 * CST];
                    float pv = __expf(v);
                    S += pv; sc += v * pv;
                    sx += pv * (float)w2; sy += pv * (float)h2;
                }
#pragma unroll
                for (int m = 2; m >= 1; m >>= 1) {
                    S += __shfl_xor(S, m); sc += __shfl_xor(sc, m);
                    sx += __shfl_xor(sx, m); sy += __shfl_xor(sy, m);
                }
                if (q4 == 0) {
                    float inv = 1.0f / S;
                    cmid[rm] = sc * inv;
                    fxm[rm] = sx * inv - (float)bx * 0.5f;
                    fym[rm] = sy * inv - (float)ay * 0.5f;
                }
            }
        }
    }
    __syncthreads();

    // flow_mid quadrant combine -> 8x8 (no-max softmax over 4)
    if (tid < 64) {
        int fy = tid >> 3, fx = tid & 7;
        int i00 = fy * 9 + fx, i01 = i00 + 1, i10 = i00 + 9, i11 = i00 + 10;
        float p0 = __expf(cmid[i00]), p1 = __expf(cmid[i01]);
        float p2 = __expf(cmid[i10]), p3 = __expf(cmid[i11]);
        float S = p0 + p1 + p2 + p3;
        float ox = 2.0f * (p0 * fxm[i00] + p1 * fxm[i01] + p2 * fxm[i10] + p3 * fxm[i11]) / S;
        float oy = 2.0f * (p0 * fym[i00] + p1 * fym[i01] + p2 * fym[i10] + p3 * fym[i11]) / S;
        int Y = (s1i * 16 + shq * 8 + fy + 4) & 511;
        int X = (s2i * 16 + swq * 8 + fx + 4) & 511;
        size_t base = (size_t)b * 2 * 512 * 512;
        f1[base + (size_t)Y * 512 + X] = ox;
        f1[base + (size_t)512 * 512 + (size_t)Y * 512 + X] = oy;
    }
}

// ---------------------------------------------------------------------------
// K5: bilinear resize (half-pixel, edge clamp) + scale, concat 4 outputs
// ---------------------------------------------------------------------------
__global__ __launch_bounds__(256) void resize_out(
    const float* __restrict__ f1e0, const float* __restrict__ f1e1,
    const float* __restrict__ f0e0, const float* __restrict__ f0e1,
    float* __restrict__ out)
{
    int idx = blockIdx.x * 256 + threadIdx.x;       // 0 .. 16777215
    int o = idx >> 22;
    int rem = idx & 4194303;
    int bc = rem >> 20;                              // b*2+ch
    int Y = (rem >> 10) & 1023;
    int X = rem & 1023;
    const float* src; int n; float invf, sc;
    if (o == 0)      { src = f1e1; n = 512; invf = 0.5f;  sc = 2.f; }
    else if (o == 1) { src = f1e0; n = 512; invf = 0.5f;  sc = 2.f; }
    else if (o == 2) { src = f0e0; n = 256; invf = 0.25f; sc = 4.f; }
    else             { src = f0e1; n = 256; invf = 0.25f; sc = 4.f; }
    float syf = ((float)Y + 0.5f) * invf - 0.5f;
    float sxf = ((float)X + 0.5f) * invf - 0.5f;
    int iy = (int)floorf(syf), ix = (int)floorf(sxf);
    float wy = syf - (float)iy, wx = sxf - (float)ix;
    int y0c = min(max(iy, 0), n - 1), y1c = min(max(iy + 1, 0), n - 1);
    int x0c = min(max(ix, 0), n - 1), x1c = min(max(ix + 1, 0), n - 1);
    const float* s = src + (size_t)bc * n * n;
    float v00 = s[(size_t)y0c * n + x0c], v01 = s[(size_t)y0c * n + x1c];
    float v10 = s[(size_t)y1c * n + x0c], v11 = s[(size_t)y1c * n + x1c];
    float v = (1.f - wy) * ((1.f - wx) * v00 + wx * v01) + wy * ((1.f - wx) * v10 + wx * v11);
    out[idx] = v * sc;
}

// ---------------------------------------------------------------------------
extern "C" void kernel_launch(void* const* d_in, const int* in_sizes, int n_in,
                              void* d_out, int out_size, void* d_ws, size_t ws_size,
                              hipStream_t stream)
{
    const float* feat0 = (const float*)d_in[0];
    const float* feat2 = (const float*)d_in[1];
    const float* wq = (const float*)d_in[2];
    const float* bq = (const float*)d_in[3];
    const float* wk = (const float*)d_in[4];
    const float* bk = (const float*)d_in[5];
    const float* btab = (const float*)d_in[6];

    char* w = (char*)d_ws;
    const size_t F = (size_t)16777216 * 2;   // bytes per bf16 NHWC field (2*256*256*128)
    __hip_bfloat16* q0 = (__hip_bfloat16*)(w);
    __hip_bfloat16* k0 = (__hip_bfloat16*)(w + F);
    __hip_bfloat16* q2 = (__hip_bfloat16*)(w + 2 * F);
    __hip_bfloat16* k2 = (__hip_bfloat16*)(w + 3 * F);
    __hip_bfloat16* in0T = (__hip_bfloat16*)(w + 4 * F);
    __hip_bfloat16* in1T = (__hip_bfloat16*)(w + 5 * F);
    __hip_bfloat16* w3q = (__hip_bfloat16*)(w + 6 * F);
    __hip_bfloat16* w3k = (__hip_bfloat16*)(w + 6 * F + 294912);
    float* f1e0 = (float*)(w + 6 * F + 2 * 294912);
    float* f1e1 = f1e0 + 1048576;   // 2*2*512*512
    float* f0e0 = f1e1 + 1048576;
    float* f0e1 = f0e0 + 262144;    // 2*2*256*256

    hipLaunchKernelGGL(fused_prep, dim3(33344), dim3(256), 0, stream,
                       feat0, feat2, wq, wk, in0T, in1T, w3q, w3k);
    hipLaunchKernelGGL(conv3x3_mfma, dim3(1024, 2), dim3(256), 0, stream,
                       in0T, in1T, w3q, w3k, bq, bk, q0, k0, q2, k2);
    hipLaunchKernelGGL(window_flow, dim3(16384), dim3(256), 0, stream,
                       q0, k0, q2, k2, btab, f1e0, f1e1, f0e0, f0e1);
    hipLaunchKernelGGL(resize_out, dim3(65536), dim3(256), 0, stream,
                       f1e0, f1e1, f0e0, f0e1, (float*)d_out);
}